// Round 5
// baseline (9059.825 us; speedup 1.0000x reference)
//
#include <hip/hip_runtime.h>

// ---------------------------------------------------------------------------
// FastCASSBlock: LN -> gradient-direction selector -> biGRU (input-proj fused
// into scan chunks) -> out_proj + residual.
// v5: 4-wave (256-thread) scan WG, 1 WG/CU => 512 regs/wave budget; whh
// resident as wf[12][8] (384 VGPR) pinned via opaque asm def; builtin MFMA
// everywhere (compiler-managed hazards).
// Workspace layout (bytes), total ~98 MiB:
//   xn   f16 [65536,256]  @ 0           (33554432)
//   gray f32 [65536]      @ 33554432    (262144)
//   flag i32 [16]         @ 33816576    (256)
//   whhP f16 [2][768,256] @ 33816832    (786432)   row-permuted, dirs contiguous
//   out_w f16 [256,512]   @ 34603264    (262144)
//   Wcomb f16 [1536,256]  @ 34865408    (786432)
//   badj f32 [1536]       @ 35651840    (6144)     bcomb + bhh folded (r,z)
//   ycat f16 [65536,512]  @ 35658240    (67108864)
// ---------------------------------------------------------------------------

#define L_   4096
#define CH   32     // scan chunk length (steps)
#define NCH  128    // L_/CH

typedef __attribute__((ext_vector_type(8))) _Float16 half8;
typedef __attribute__((ext_vector_type(4))) float f32x4;

__device__ __forceinline__ unsigned short f2h(float f) {
  _Float16 h = (_Float16)f;
  return __builtin_bit_cast(unsigned short, h);
}
__device__ __forceinline__ float h2f(unsigned short u) {
  return (float)__builtin_bit_cast(_Float16, u);
}
__device__ __forceinline__ float sigm(float x) {
  return __builtin_amdgcn_rcpf(1.f + __expf(-x));
}
__device__ __forceinline__ float tanhf_(float x) {
  return 1.f - 2.f * __builtin_amdgcn_rcpf(1.f + __expf(2.f * x));
}

// --------------------------- f32 -> f16 convert ----------------------------
__global__ __launch_bounds__(256) void k_f2h(const float* __restrict__ in,
                                             unsigned short* __restrict__ out,
                                             int n) {
  int i = blockIdx.x * 256 + threadIdx.x;
  if (i < n) out[i] = f2h(in[i]);
}

// ---------------- whh row-permute + convert (4-wave layout) -----------------
// permuted row p = (wv*12 + j)*16 + l  <->  original row g*256 + u,
// g = j>>2 (gate r/z/n), u = wv*64 + (j&3)*16 + l.
__global__ __launch_bounds__(256) void k_whhP(const float* __restrict__ whh_f,
                                              const float* __restrict__ whh_b,
                                              unsigned short* __restrict__ whhP) {
  const int x = blockIdx.x;          // 0..1535
  const int dir = x >= 768;
  const int p = dir ? (x - 768) : x;
  const int wv = p / 192;
  const int r2 = p - wv * 192;
  const int j = r2 >> 4;
  const int l = r2 & 15;
  const int g = j >> 2;
  const int u = wv * 64 + (j & 3) * 16 + l;
  const float* src = (dir ? whh_b : whh_f) + (long)(g * 256 + u) * 256;
  whhP[(long)x * 256 + threadIdx.x] = f2h(src[threadIdx.x]);
}

// ------------------- Wcomb[n,c] = sum_j wih[n,j]*in_w[j,c] -----------------
__global__ __launch_bounds__(256) void k_wcomb(const float* __restrict__ wih_f,
                                               const float* __restrict__ wih_b,
                                               const float* __restrict__ in_w,
                                               unsigned short* __restrict__ wcomb) {
  const int n = blockIdx.x;  // 0..1535
  const float* wrow = (n < 768) ? (wih_f + (long)n * 512)
                                : (wih_b + (long)(n - 768) * 512);
  const int k = threadIdx.x;  // 0..255
  float acc = 0.f;
  for (int j = 0; j < 512; ++j) acc += wrow[j] * in_w[j * 256 + k];
  wcomb[(long)n * 256 + k] = f2h(acc);
}

// -- badj[n] = bih[n] + sum_j wih[n,j]*in_b[j] (+ bhh[n] for r/z slots) ------
__global__ __launch_bounds__(256) void k_bcomb(const float* __restrict__ wih_f,
                                               const float* __restrict__ wih_b,
                                               const float* __restrict__ in_b,
                                               const float* __restrict__ bih_f,
                                               const float* __restrict__ bih_b,
                                               const float* __restrict__ bhh_f,
                                               const float* __restrict__ bhh_b,
                                               float* __restrict__ badj) {
  int n = blockIdx.x * 256 + threadIdx.x;
  if (n >= 1536) return;
  const int dir = n >= 768;
  const int g = dir ? (n - 768) : n;
  const float* wrow = (dir ? wih_b : wih_f) + (long)g * 512;
  float acc = (dir ? bih_b : bih_f)[g];
  for (int j = 0; j < 512; ++j) acc += wrow[j] * in_b[j];
  if (g < 512) acc += (dir ? bhh_b : bhh_f)[g];  // fold bhh for r,z gates
  badj[n] = acc;
}

// --------------------------- LayerNorm + gray ------------------------------
__global__ __launch_bounds__(256) void k_ln(const float* __restrict__ x,
                                            const float* __restrict__ gamma,
                                            const float* __restrict__ beta,
                                            unsigned short* __restrict__ xn,
                                            float* __restrict__ gray) {
  const int lane = threadIdx.x & 63;
  const long pix = (long)blockIdx.x * 4 + (threadIdx.x >> 6);
  const float4 v = *(const float4*)(x + pix * 256 + lane * 4);
  float s = v.x + v.y + v.z + v.w;
  float s2 = v.x * v.x + v.y * v.y + v.z * v.z + v.w * v.w;
#pragma unroll
  for (int off = 32; off > 0; off >>= 1) {
    s += __shfl_xor(s, off, 64);
    s2 += __shfl_xor(s2, off, 64);
  }
  const float mu = s * (1.f / 256.f);
  const float var = fmaxf(s2 * (1.f / 256.f) - mu * mu, 0.f);
  const float rstd = rsqrtf(var + 1e-5f);
  const float4 gm = *(const float4*)(gamma + lane * 4);
  const float4 bt = *(const float4*)(beta + lane * 4);
  float o0 = (v.x - mu) * rstd * gm.x + bt.x;
  float o1 = (v.y - mu) * rstd * gm.y + bt.y;
  float o2 = (v.z - mu) * rstd * gm.z + bt.z;
  float o3 = (v.w - mu) * rstd * gm.w + bt.w;
  ushort4 o;
  o.x = f2h(o0); o.y = f2h(o1); o.z = f2h(o2); o.w = f2h(o3);
  *(ushort4*)(xn + pix * 256 + lane * 4) = o;
  float gs = o0 + o1 + o2 + o3;
#pragma unroll
  for (int off = 32; off > 0; off >>= 1) gs += __shfl_xor(gs, off, 64);
  if (lane == 0) gray[pix] = gs * (1.f / 256.f);
}

// --------------------- gradient-direction selector -------------------------
__device__ __forceinline__ int refl64(int m) {
  return m < 0 ? -m : (m > 63 ? 126 - m : m);
}

__global__ __launch_bounds__(256) void k_sel(const float* __restrict__ gray,
                                             const float* __restrict__ w1,
                                             const float* __restrict__ b1,
                                             const float* __restrict__ w2,
                                             const float* __restrict__ b2,
                                             int* __restrict__ flag) {
  __shared__ float g[64][65];
  __shared__ float part[4][4];
  const int b = blockIdx.x;
  const int tid = threadIdx.x;
  for (int r = 0; r < 16; ++r) {
    int p = tid + 256 * r;
    g[p >> 6][p & 63] = gray[(long)b * 4096 + p];
  }
  __syncthreads();
  const float S = 66.f / 64.f;
  float sh = 0.f, sv = 0.f, sd = 0.f, sa = 0.f;
  for (int rr = 0; rr < 16; ++rr) {
    int p = tid + 256 * rr;
    int h = p >> 6, w = p & 63;
    float srci = (h + 0.5f) * S - 0.5f;
    int i0 = (int)srci;
    float ai = srci - (float)i0;
    int i1 = i0 + 1; if (i1 > 65) i1 = 65;
    int r0 = refl64(i0 - 1), r1 = refl64(i1 - 1);
    int wl = w ? (w - 1) : 1;
    int wr2 = (w == 63) ? 62 : (w + 1);
    float GH0 = fabsf(g[r0][wr2] - g[r0][wl]);
    float GH1 = fabsf(g[r1][wr2] - g[r1][wl]);
    float ghr = GH0 + ai * (GH1 - GH0);
    float srcj = (w + 0.5f) * S - 0.5f;
    int j0 = (int)srcj;
    float aj = srcj - (float)j0;
    int j1 = j0 + 1; if (j1 > 65) j1 = 65;
    int c0 = refl64(j0 - 1), c1 = refl64(j1 - 1);
    int hu = h ? (h - 1) : 1;
    int hd = (h == 63) ? 62 : (h + 1);
    float GV0 = fabsf(g[hd][c0] - g[hu][c0]);
    float GV1 = fabsf(g[hd][c1] - g[hu][c1]);
    float gvr = GV0 + aj * (GV1 - GV0);
    float wt = ((h == 0 || h == 63) ? 2.f : 3.f) *
               ((w == 0 || w == 63) ? 2.f : 3.f);
    sh += wt * ghr;
    sv += wt * gvr;
    sd += wt * 0.5f * (ghr + gvr);
    sa += wt * fabsf(ghr - gvr);
  }
#pragma unroll
  for (int off = 32; off > 0; off >>= 1) {
    sh += __shfl_xor(sh, off, 64);
    sv += __shfl_xor(sv, off, 64);
    sd += __shfl_xor(sd, off, 64);
    sa += __shfl_xor(sa, off, 64);
  }
  if ((tid & 63) == 0) {
    part[tid >> 6][0] = sh; part[tid >> 6][1] = sv;
    part[tid >> 6][2] = sd; part[tid >> 6][3] = sa;
  }
  __syncthreads();
  if (tid == 0) {
    float sc[4];
    for (int k = 0; k < 4; ++k)
      sc[k] = (part[0][k] + part[1][k] + part[2][k] + part[3][k]) * (1.f / 36864.f);
    float logits[4];
    for (int k = 0; k < 4; ++k) logits[k] = b2[k];
    for (int j = 0; j < 32; ++j) {
      float hj = b1[j];
      for (int i = 0; i < 4; ++i) hj += sc[i] * w1[j * 4 + i];
      hj = fmaxf(hj, 0.f);
      for (int k = 0; k < 4; ++k) logits[k] += hj * w2[k * 32 + j];
    }
    int idx = 0;
    float best = logits[0];
    for (int k = 1; k < 4; ++k)
      if (logits[k] > best) { best = logits[k]; idx = k; }
    flag[b] = (idx == 1) ? 1 : 0;
  }
}

// --------------------------- out-proj GEMM ---------------------------------
__global__ __launch_bounds__(256) void k_gemm(const unsigned short* __restrict__ A,
                                              const unsigned short* __restrict__ Bw,
                                              const float* __restrict__ bias,
                                              const float* __restrict__ resid,
                                              float* __restrict__ out,
                                              int K, int N) {
  __shared__ unsigned short Al[128][40];
  __shared__ unsigned short Bl[128][40];
  const int tid = threadIdx.x;
  const long m0 = (long)blockIdx.x * 128;
  const int n0 = blockIdx.y * 128;
  const int rA = tid >> 2;
  const int cp = (tid & 3) * 8;

  const unsigned short* a0p = A + (m0 + rA) * K + cp;
  const unsigned short* a1p = A + (m0 + rA + 64) * K + cp;
  const unsigned short* b0p = Bw + (long)(n0 + rA) * K + cp;
  const unsigned short* b1p = Bw + (long)(n0 + rA + 64) * K + cp;

  const int wv = tid >> 6, lane = tid & 63;
  const int wm = (wv >> 1) * 64, wn = (wv & 1) * 64;
  const int fr = lane & 15, fq = lane >> 4;

  const f32x4 zero4 = {0.f, 0.f, 0.f, 0.f};
  f32x4 acc[4][4];
#pragma unroll
  for (int i = 0; i < 4; ++i)
#pragma unroll
    for (int j = 0; j < 4; ++j) acc[i][j] = zero4;

  for (int k0 = 0; k0 < K; k0 += 32) {
    half8 va0 = *(const half8*)(a0p + k0);
    half8 va1 = *(const half8*)(a1p + k0);
    half8 vb0 = *(const half8*)(b0p + k0);
    half8 vb1 = *(const half8*)(b1p + k0);
    __syncthreads();
    *(half8*)&Al[rA][cp] = va0;
    *(half8*)&Al[rA + 64][cp] = va1;
    *(half8*)&Bl[rA][cp] = vb0;
    *(half8*)&Bl[rA + 64][cp] = vb1;
    __syncthreads();
    half8 af[4], bf[4];
#pragma unroll
    for (int i = 0; i < 4; ++i) af[i] = *(const half8*)&Al[wm + i * 16 + fr][fq * 8];
#pragma unroll
    for (int j = 0; j < 4; ++j) bf[j] = *(const half8*)&Bl[wn + j * 16 + fr][fq * 8];
#pragma unroll
    for (int i = 0; i < 4; ++i)
#pragma unroll
      for (int j = 0; j < 4; ++j)
        acc[i][j] = __builtin_amdgcn_mfma_f32_16x16x32_f16(af[i], bf[j], acc[i][j], 0, 0, 0);
  }

#pragma unroll
  for (int j = 0; j < 4; ++j) {
    const int col = n0 + wn + j * 16 + fr;
    const float bv = bias[col];
#pragma unroll
    for (int i = 0; i < 4; ++i) {
      const long mbase = m0 + wm + i * 16 + fq * 4;
#pragma unroll
      for (int r = 0; r < 4; ++r) {
        const long m = mbase + r;
        out[m * N + col] = acc[i][j][r] + bv + resid[m * N + col];
      }
    }
  }
}

// ------------------------------- GRU scan v5 --------------------------------
// One WG per (batch, direction): 32 WGs, 256 threads (4 waves), 1 WG/CU.
// Budget: 512 regs/wave.  whhP resident as wf[12][8] (384 VGPR), pinned by an
// opaque asm def (non-rematerializable).  Wave wv owns units [wv*64,wv*64+64);
// tile j: gate g=j>>2, quarter q=j&3.  After the M=16-padded MFMA chain,
// lane l<16 holds gh[g][wv*64+q*16+l] in acc[j][0]; gate math in-lane.
// One barrier/step; per-chunk input-proj GEMM; y staged in LDS per chunk.
__global__ __launch_bounds__(256, 1) void k_scan(
    const unsigned short* __restrict__ xn,
    const unsigned short* __restrict__ wcomb,
    const float* __restrict__ badj,
    const unsigned short* __restrict__ whhP,
    const float* __restrict__ bhhf,
    const float* __restrict__ bhhb,
    const int* __restrict__ flag,
    unsigned short* __restrict__ ycat) {
  const int dir = blockIdx.x & 1;
  const int b = blockIdx.x >> 1;
  const unsigned short* whh = whhP + (long)dir * (768 * 256);
  const float* bhh = dir ? bhhb : bhhf;
  const unsigned short* wcd = wcomb + (long)dir * (768 * 256);
  const float* bcd = badj + dir * 768;
  const int tid = threadIdx.x;
  const int wv = tid >> 6;        // 0..3
  const int lane = tid & 63;
  const int fr = lane & 15;
  const int fq = lane >> 4;
  const int fb = flag[b];

  // resident permuted recurrent weights: wave wv -> rows (wv*12+j)*16 + fr
  half8 wf[12][8];
#pragma unroll
  for (int j = 0; j < 12; ++j) {
    const unsigned short* wrow =
        whh + (long)((wv * 12 + j) * 16 + fr) * 256 + fq * 8;
#pragma unroll
    for (int s = 0; s < 8; ++s) wf[j][s] = *(const half8*)(wrow + s * 32);
  }
  // opaque def: pins each fragment in a register, blocks remat-from-memory
#pragma unroll
  for (int j = 0; j < 12; ++j)
#pragma unroll
    for (int s = 0; s < 8; ++s) asm volatile("" : "+v"(wf[j][s]));

  __shared__ unsigned short xplds[CH][768];   // 48 KiB
  __shared__ unsigned short ylds[CH][256];    // 16 KiB
  __shared__ unsigned short hbuf[2][272];     // dbuf h + 16B zero pad @256

  float Bnh[4], h[4];
#pragma unroll
  for (int q = 0; q < 4; ++q) { Bnh[q] = 0.f; h[q] = 0.f; }
  if (lane < 16) {
#pragma unroll
    for (int q = 0; q < 4; ++q) Bnh[q] = bhh[512 + wv * 64 + q * 16 + fr];
  }
  hbuf[0][tid] = 0;
  if (tid < 16) {
    hbuf[0][256 + tid] = 0;
    hbuf[1][256 + tid] = 0;
  }
  __syncthreads();

  const long xnb = (long)b * 4096;
  unsigned short* yb = ycat + (long)b * (L_ * 512) + dir * 256;

  const f32x4 zero4 = {0.f, 0.f, 0.f, 0.f};
  int pb = 0;  // current h buffer

  for (int c = 0; c < NCH; ++c) {
    const int cc = dir ? (NCH - 1 - c) : c;
    const int t0 = cc * CH;

    // ---- flush previous chunk's y from LDS to global (skip first) ----
    if (c > 0) {
      const int pt0 = (dir ? (NCH - c) : (c - 1)) * CH;
#pragma unroll
      for (int k = 0; k < 4; ++k) {
        const int idx = tid + 256 * k;
        const int ts = idx >> 5;
        const int cl = (idx & 31) * 8;
        half8 v = *(const half8*)&ylds[ts][cl];
        *(half8*)(yb + (long)(pt0 + ts) * 512 + cl) = v;
      }
    }

    // ---- chunk GEMM: xplds = seq[t0..t0+31] @ wcd.T + bias ----
    const unsigned short* arow0;
    const unsigned short* arow1;
    {
      int t = t0 + fr;
      int p = fb ? (((t & 63) << 6) | (t >> 6)) : t;
      arow0 = xn + (xnb + p) * 256 + fq * 8;
      t = t0 + 16 + fr;
      p = fb ? (((t & 63) << 6) | (t >> 6)) : t;
      arow1 = xn + (xnb + p) * 256 + fq * 8;
    }
#pragma unroll
    for (int hf = 0; hf < 4; ++hf) {
      f32x4 acc0[3], acc1[3];
#pragma unroll
      for (int j = 0; j < 3; ++j) { acc0[j] = zero4; acc1[j] = zero4; }
#pragma unroll
      for (int s = 0; s < 8; ++s) {
        half8 a0 = *(const half8*)(arow0 + s * 32);
        half8 a1 = *(const half8*)(arow1 + s * 32);
#pragma unroll
        for (int j = 0; j < 3; ++j) {
          const int n = wv * 192 + hf * 48 + j * 16 + fr;
          half8 bfr = *(const half8*)(wcd + (long)n * 256 + s * 32 + fq * 8);
          acc0[j] = __builtin_amdgcn_mfma_f32_16x16x32_f16(a0, bfr, acc0[j], 0, 0, 0);
          acc1[j] = __builtin_amdgcn_mfma_f32_16x16x32_f16(a1, bfr, acc1[j], 0, 0, 0);
        }
      }
#pragma unroll
      for (int j = 0; j < 3; ++j) {
        const int n = wv * 192 + hf * 48 + j * 16 + fr;
        const float bv = bcd[n];
#pragma unroll
        for (int r = 0; r < 4; ++r) {
          xplds[fq * 4 + r][n] = f2h(acc0[j][r] + bv);
          xplds[16 + fq * 4 + r][n] = f2h(acc1[j][r] + bv);
        }
      }
    }
    __syncthreads();  // xplds ready; ylds free

    // ---- sequential GRU steps (ONE barrier each) ----
    for (int lt = 0; lt < CH; ++lt) {
      const int ts = dir ? (CH - 1 - lt) : lt;
      // prefetch gate inputs (independent of h)
      float xr[4], xz[4], xnv[4];
#pragma unroll
      for (int q = 0; q < 4; ++q) { xr[q] = 0.f; xz[q] = 0.f; xnv[q] = 0.f; }
      if (lane < 16) {
#pragma unroll
        for (int q = 0; q < 4; ++q) {
          const int u = wv * 64 + q * 16 + fr;
          xr[q] = h2f(xplds[ts][u]);
          xz[q] = h2f(xplds[ts][256 + u]);
          xnv[q] = h2f(xplds[ts][512 + u]);
        }
      }
      // gh = h @ whhP.T : M=16-padded MFMA, row 0 = h (lanes fr!=0 read the
      // 16B zero pad at offset 256 -> branchless zero rows).
      f32x4 acc[12];
#pragma unroll
      for (int j = 0; j < 12; ++j) acc[j] = zero4;
#pragma unroll
      for (int s = 0; s < 8; ++s) {
        const half8 a =
            *(const half8*)&hbuf[pb][(fr == 0) ? (s * 32 + fq * 8) : 256];
#pragma unroll
        for (int j = 0; j < 12; ++j)
          acc[j] = __builtin_amdgcn_mfma_f32_16x16x32_f16(a, wf[j][s], acc[j], 0, 0, 0);
      }
      // in-lane gate math: 4 units per lane (q=0..3)
      if (lane < 16) {
#pragma unroll
        for (int q = 0; q < 4; ++q) {
          const int u = wv * 64 + q * 16 + fr;
          float r = sigm(xr[q] + acc[q][0]);
          float z = sigm(xz[q] + acc[4 + q][0]);
          float n = tanhf_(xnv[q] + r * (acc[8 + q][0] + Bnh[q]));
          h[q] = n + z * (h[q] - n);
          unsigned short hb = f2h(h[q]);
          hbuf[pb ^ 1][u] = hb;
          ylds[ts][u] = hb;
        }
      }
      pb ^= 1;
      __syncthreads();
    }
  }
  // final chunk's y flush
  {
    const int pt0 = (dir ? 0 : (NCH - 1)) * CH;
#pragma unroll
    for (int k = 0; k < 4; ++k) {
      const int idx = tid + 256 * k;
      const int ts = idx >> 5;
      const int cl = (idx & 31) * 8;
      half8 v = *(const half8*)&ylds[ts][cl];
      *(half8*)(yb + (long)(pt0 + ts) * 512 + cl) = v;
    }
  }
}

// ------------------------------- launcher ----------------------------------
extern "C" void kernel_launch(void* const* d_in, const int* in_sizes, int n_in,
                              void* d_out, int out_size, void* d_ws, size_t ws_size,
                              hipStream_t stream) {
  (void)in_sizes; (void)n_in; (void)out_size; (void)ws_size;
  const float* x     = (const float*)d_in[0];
  const float* lng   = (const float*)d_in[1];
  const float* lnb   = (const float*)d_in[2];
  const float* w1    = (const float*)d_in[3];
  const float* b1    = (const float*)d_in[4];
  const float* w2    = (const float*)d_in[5];
  const float* b2    = (const float*)d_in[6];
  const float* in_w  = (const float*)d_in[7];
  const float* in_b  = (const float*)d_in[8];
  const float* wih_f = (const float*)d_in[9];
  const float* whh_f = (const float*)d_in[10];
  const float* bih_f = (const float*)d_in[11];
  const float* bhh_f = (const float*)d_in[12];
  const float* wih_b = (const float*)d_in[13];
  const float* whh_b = (const float*)d_in[14];
  const float* bih_b = (const float*)d_in[15];
  const float* bhh_b = (const float*)d_in[16];
  const float* out_w = (const float*)d_in[17];
  const float* out_b = (const float*)d_in[18];

  char* ws = (char*)d_ws;
  unsigned short* xn     = (unsigned short*)(ws + 0);
  float*          gray   = (float*)(ws + 33554432);
  int*            flag   = (int*)(ws + 33816576);
  unsigned short* whhP   = (unsigned short*)(ws + 33816832);
  unsigned short* outw16 = (unsigned short*)(ws + 34603264);
  unsigned short* wcomb  = (unsigned short*)(ws + 34865408);
  float*          badj   = (float*)(ws + 35651840);
  unsigned short* ycat   = (unsigned short*)(ws + 35658240);

  k_whhP<<<1536, 256, 0, stream>>>(whh_f, whh_b, whhP);
  k_f2h<<<512, 256, 0, stream>>>(out_w, outw16, 131072);
  k_wcomb<<<1536, 256, 0, stream>>>(wih_f, wih_b, in_w, wcomb);
  k_bcomb<<<6, 256, 0, stream>>>(wih_f, wih_b, in_b, bih_f, bih_b,
                                 bhh_f, bhh_b, badj);
  k_ln<<<16384, 256, 0, stream>>>(x, lng, lnb, xn, gray);
  k_sel<<<16, 256, 0, stream>>>(gray, w1, b1, w2, b2, flag);
  k_scan<<<32, 256, 0, stream>>>(xn, wcomb, badj, whhP,
                                 bhh_f, bhh_b, flag, ycat);
  dim3 gout(512, 2);
  k_gemm<<<gout, 256, 0, stream>>>(ycat, outw16, out_b, x, (float*)d_out, 512, 256);
}

// Round 6
// 8355.939 us; speedup vs baseline: 1.0842x; 1.0842x over previous
//
#include <hip/hip_runtime.h>

// ---------------------------------------------------------------------------
// FastCASSBlock: LN -> gradient-direction selector -> biGRU (input-proj fused
// into scan chunks) -> out_proj + residual.
// v6: v5 geometry (4-wave WG, 1 WG/CU, 512 regs/wave) with whh residency
// split across the unified register file: 8 tiles pinned to AGPRs (256) +
// 4 tiles pinned to VGPRs (128). Builtin MFMA (compiler-managed hazards)
// reads B directly from AGPR/VGPR.
// Workspace layout (bytes), total ~98 MiB:
//   xn   f16 [65536,256]  @ 0           (33554432)
//   gray f32 [65536]      @ 33554432    (262144)
//   flag i32 [16]         @ 33816576    (256)
//   whhP f16 [2][768,256] @ 33816832    (786432)   row-permuted, dirs contiguous
//   out_w f16 [256,512]   @ 34603264    (262144)
//   Wcomb f16 [1536,256]  @ 34865408    (786432)
//   badj f32 [1536]       @ 35651840    (6144)     bcomb + bhh folded (r,z)
//   ycat f16 [65536,512]  @ 35658240    (67108864)
// ---------------------------------------------------------------------------

#define L_   4096
#define CH   32     // scan chunk length (steps)
#define NCH  128    // L_/CH

typedef __attribute__((ext_vector_type(8))) _Float16 half8;
typedef __attribute__((ext_vector_type(4))) float f32x4;

__device__ __forceinline__ unsigned short f2h(float f) {
  _Float16 h = (_Float16)f;
  return __builtin_bit_cast(unsigned short, h);
}
__device__ __forceinline__ float h2f(unsigned short u) {
  return (float)__builtin_bit_cast(_Float16, u);
}
__device__ __forceinline__ float sigm(float x) {
  return __builtin_amdgcn_rcpf(1.f + __expf(-x));
}
__device__ __forceinline__ float tanhf_(float x) {
  return 1.f - 2.f * __builtin_amdgcn_rcpf(1.f + __expf(2.f * x));
}

// --------------------------- f32 -> f16 convert ----------------------------
__global__ __launch_bounds__(256) void k_f2h(const float* __restrict__ in,
                                             unsigned short* __restrict__ out,
                                             int n) {
  int i = blockIdx.x * 256 + threadIdx.x;
  if (i < n) out[i] = f2h(in[i]);
}

// ---------------- whh row-permute + convert (4-wave layout) -----------------
// permuted row p = (wv*12 + j)*16 + l  <->  original row g*256 + u,
// g = j>>2 (gate r/z/n), u = wv*64 + (j&3)*16 + l.
__global__ __launch_bounds__(256) void k_whhP(const float* __restrict__ whh_f,
                                              const float* __restrict__ whh_b,
                                              unsigned short* __restrict__ whhP) {
  const int x = blockIdx.x;          // 0..1535
  const int dir = x >= 768;
  const int p = dir ? (x - 768) : x;
  const int wv = p / 192;
  const int r2 = p - wv * 192;
  const int j = r2 >> 4;
  const int l = r2 & 15;
  const int g = j >> 2;
  const int u = wv * 64 + (j & 3) * 16 + l;
  const float* src = (dir ? whh_b : whh_f) + (long)(g * 256 + u) * 256;
  whhP[(long)x * 256 + threadIdx.x] = f2h(src[threadIdx.x]);
}

// ------------------- Wcomb[n,c] = sum_j wih[n,j]*in_w[j,c] -----------------
__global__ __launch_bounds__(256) void k_wcomb(const float* __restrict__ wih_f,
                                               const float* __restrict__ wih_b,
                                               const float* __restrict__ in_w,
                                               unsigned short* __restrict__ wcomb) {
  const int n = blockIdx.x;  // 0..1535
  const float* wrow = (n < 768) ? (wih_f + (long)n * 512)
                                : (wih_b + (long)(n - 768) * 512);
  const int k = threadIdx.x;  // 0..255
  float acc = 0.f;
  for (int j = 0; j < 512; ++j) acc += wrow[j] * in_w[j * 256 + k];
  wcomb[(long)n * 256 + k] = f2h(acc);
}

// -- badj[n] = bih[n] + sum_j wih[n,j]*in_b[j] (+ bhh[n] for r/z slots) ------
__global__ __launch_bounds__(256) void k_bcomb(const float* __restrict__ wih_f,
                                               const float* __restrict__ wih_b,
                                               const float* __restrict__ in_b,
                                               const float* __restrict__ bih_f,
                                               const float* __restrict__ bih_b,
                                               const float* __restrict__ bhh_f,
                                               const float* __restrict__ bhh_b,
                                               float* __restrict__ badj) {
  int n = blockIdx.x * 256 + threadIdx.x;
  if (n >= 1536) return;
  const int dir = n >= 768;
  const int g = dir ? (n - 768) : n;
  const float* wrow = (dir ? wih_b : wih_f) + (long)g * 512;
  float acc = (dir ? bih_b : bih_f)[g];
  for (int j = 0; j < 512; ++j) acc += wrow[j] * in_b[j];
  if (g < 512) acc += (dir ? bhh_b : bhh_f)[g];  // fold bhh for r,z gates
  badj[n] = acc;
}

// --------------------------- LayerNorm + gray ------------------------------
__global__ __launch_bounds__(256) void k_ln(const float* __restrict__ x,
                                            const float* __restrict__ gamma,
                                            const float* __restrict__ beta,
                                            unsigned short* __restrict__ xn,
                                            float* __restrict__ gray) {
  const int lane = threadIdx.x & 63;
  const long pix = (long)blockIdx.x * 4 + (threadIdx.x >> 6);
  const float4 v = *(const float4*)(x + pix * 256 + lane * 4);
  float s = v.x + v.y + v.z + v.w;
  float s2 = v.x * v.x + v.y * v.y + v.z * v.z + v.w * v.w;
#pragma unroll
  for (int off = 32; off > 0; off >>= 1) {
    s += __shfl_xor(s, off, 64);
    s2 += __shfl_xor(s2, off, 64);
  }
  const float mu = s * (1.f / 256.f);
  const float var = fmaxf(s2 * (1.f / 256.f) - mu * mu, 0.f);
  const float rstd = rsqrtf(var + 1e-5f);
  const float4 gm = *(const float4*)(gamma + lane * 4);
  const float4 bt = *(const float4*)(beta + lane * 4);
  float o0 = (v.x - mu) * rstd * gm.x + bt.x;
  float o1 = (v.y - mu) * rstd * gm.y + bt.y;
  float o2 = (v.z - mu) * rstd * gm.z + bt.z;
  float o3 = (v.w - mu) * rstd * gm.w + bt.w;
  ushort4 o;
  o.x = f2h(o0); o.y = f2h(o1); o.z = f2h(o2); o.w = f2h(o3);
  *(ushort4*)(xn + pix * 256 + lane * 4) = o;
  float gs = o0 + o1 + o2 + o3;
#pragma unroll
  for (int off = 32; off > 0; off >>= 1) gs += __shfl_xor(gs, off, 64);
  if (lane == 0) gray[pix] = gs * (1.f / 256.f);
}

// --------------------- gradient-direction selector -------------------------
__device__ __forceinline__ int refl64(int m) {
  return m < 0 ? -m : (m > 63 ? 126 - m : m);
}

__global__ __launch_bounds__(256) void k_sel(const float* __restrict__ gray,
                                             const float* __restrict__ w1,
                                             const float* __restrict__ b1,
                                             const float* __restrict__ w2,
                                             const float* __restrict__ b2,
                                             int* __restrict__ flag) {
  __shared__ float g[64][65];
  __shared__ float part[4][4];
  const int b = blockIdx.x;
  const int tid = threadIdx.x;
  for (int r = 0; r < 16; ++r) {
    int p = tid + 256 * r;
    g[p >> 6][p & 63] = gray[(long)b * 4096 + p];
  }
  __syncthreads();
  const float S = 66.f / 64.f;
  float sh = 0.f, sv = 0.f, sd = 0.f, sa = 0.f;
  for (int rr = 0; rr < 16; ++rr) {
    int p = tid + 256 * rr;
    int h = p >> 6, w = p & 63;
    float srci = (h + 0.5f) * S - 0.5f;
    int i0 = (int)srci;
    float ai = srci - (float)i0;
    int i1 = i0 + 1; if (i1 > 65) i1 = 65;
    int r0 = refl64(i0 - 1), r1 = refl64(i1 - 1);
    int wl = w ? (w - 1) : 1;
    int wr2 = (w == 63) ? 62 : (w + 1);
    float GH0 = fabsf(g[r0][wr2] - g[r0][wl]);
    float GH1 = fabsf(g[r1][wr2] - g[r1][wl]);
    float ghr = GH0 + ai * (GH1 - GH0);
    float srcj = (w + 0.5f) * S - 0.5f;
    int j0 = (int)srcj;
    float aj = srcj - (float)j0;
    int j1 = j0 + 1; if (j1 > 65) j1 = 65;
    int c0 = refl64(j0 - 1), c1 = refl64(j1 - 1);
    int hu = h ? (h - 1) : 1;
    int hd = (h == 63) ? 62 : (h + 1);
    float GV0 = fabsf(g[hd][c0] - g[hu][c0]);
    float GV1 = fabsf(g[hd][c1] - g[hu][c1]);
    float gvr = GV0 + aj * (GV1 - GV0);
    float wt = ((h == 0 || h == 63) ? 2.f : 3.f) *
               ((w == 0 || w == 63) ? 2.f : 3.f);
    sh += wt * ghr;
    sv += wt * gvr;
    sd += wt * 0.5f * (ghr + gvr);
    sa += wt * fabsf(ghr - gvr);
  }
#pragma unroll
  for (int off = 32; off > 0; off >>= 1) {
    sh += __shfl_xor(sh, off, 64);
    sv += __shfl_xor(sv, off, 64);
    sd += __shfl_xor(sd, off, 64);
    sa += __shfl_xor(sa, off, 64);
  }
  if ((tid & 63) == 0) {
    part[tid >> 6][0] = sh; part[tid >> 6][1] = sv;
    part[tid >> 6][2] = sd; part[tid >> 6][3] = sa;
  }
  __syncthreads();
  if (tid == 0) {
    float sc[4];
    for (int k = 0; k < 4; ++k)
      sc[k] = (part[0][k] + part[1][k] + part[2][k] + part[3][k]) * (1.f / 36864.f);
    float logits[4];
    for (int k = 0; k < 4; ++k) logits[k] = b2[k];
    for (int j = 0; j < 32; ++j) {
      float hj = b1[j];
      for (int i = 0; i < 4; ++i) hj += sc[i] * w1[j * 4 + i];
      hj = fmaxf(hj, 0.f);
      for (int k = 0; k < 4; ++k) logits[k] += hj * w2[k * 32 + j];
    }
    int idx = 0;
    float best = logits[0];
    for (int k = 1; k < 4; ++k)
      if (logits[k] > best) { best = logits[k]; idx = k; }
    flag[b] = (idx == 1) ? 1 : 0;
  }
}

// --------------------------- out-proj GEMM ---------------------------------
__global__ __launch_bounds__(256) void k_gemm(const unsigned short* __restrict__ A,
                                              const unsigned short* __restrict__ Bw,
                                              const float* __restrict__ bias,
                                              const float* __restrict__ resid,
                                              float* __restrict__ out,
                                              int K, int N) {
  __shared__ unsigned short Al[128][40];
  __shared__ unsigned short Bl[128][40];
  const int tid = threadIdx.x;
  const long m0 = (long)blockIdx.x * 128;
  const int n0 = blockIdx.y * 128;
  const int rA = tid >> 2;
  const int cp = (tid & 3) * 8;

  const unsigned short* a0p = A + (m0 + rA) * K + cp;
  const unsigned short* a1p = A + (m0 + rA + 64) * K + cp;
  const unsigned short* b0p = Bw + (long)(n0 + rA) * K + cp;
  const unsigned short* b1p = Bw + (long)(n0 + rA + 64) * K + cp;

  const int wv = tid >> 6, lane = tid & 63;
  const int wm = (wv >> 1) * 64, wn = (wv & 1) * 64;
  const int fr = lane & 15, fq = lane >> 4;

  const f32x4 zero4 = {0.f, 0.f, 0.f, 0.f};
  f32x4 acc[4][4];
#pragma unroll
  for (int i = 0; i < 4; ++i)
#pragma unroll
    for (int j = 0; j < 4; ++j) acc[i][j] = zero4;

  for (int k0 = 0; k0 < K; k0 += 32) {
    half8 va0 = *(const half8*)(a0p + k0);
    half8 va1 = *(const half8*)(a1p + k0);
    half8 vb0 = *(const half8*)(b0p + k0);
    half8 vb1 = *(const half8*)(b1p + k0);
    __syncthreads();
    *(half8*)&Al[rA][cp] = va0;
    *(half8*)&Al[rA + 64][cp] = va1;
    *(half8*)&Bl[rA][cp] = vb0;
    *(half8*)&Bl[rA + 64][cp] = vb1;
    __syncthreads();
    half8 af[4], bf[4];
#pragma unroll
    for (int i = 0; i < 4; ++i) af[i] = *(const half8*)&Al[wm + i * 16 + fr][fq * 8];
#pragma unroll
    for (int j = 0; j < 4; ++j) bf[j] = *(const half8*)&Bl[wn + j * 16 + fr][fq * 8];
#pragma unroll
    for (int i = 0; i < 4; ++i)
#pragma unroll
      for (int j = 0; j < 4; ++j)
        acc[i][j] = __builtin_amdgcn_mfma_f32_16x16x32_f16(af[i], bf[j], acc[i][j], 0, 0, 0);
  }

#pragma unroll
  for (int j = 0; j < 4; ++j) {
    const int col = n0 + wn + j * 16 + fr;
    const float bv = bias[col];
#pragma unroll
    for (int i = 0; i < 4; ++i) {
      const long mbase = m0 + wm + i * 16 + fq * 4;
#pragma unroll
      for (int r = 0; r < 4; ++r) {
        const long m = mbase + r;
        out[m * N + col] = acc[i][j][r] + bv + resid[m * N + col];
      }
    }
  }
}

// ------------------------------- GRU scan v6 --------------------------------
// One WG per (batch, direction): 32 WGs, 256 threads (4 waves), 1 WG/CU.
// Unified-file budget 512 regs/wave = 256 arch VGPR + 256 AGPR.
// whhP resident as wf[12][8] (384 regs): tiles 0..7 pinned to AGPRs (256),
// tiles 8..11 pinned to VGPRs (128); ~128 VGPRs left for the working set.
// Builtin MFMA reads B from AGPR or VGPR directly (hazards compiler-managed).
__global__ __launch_bounds__(256, 1) void k_scan(
    const unsigned short* __restrict__ xn,
    const unsigned short* __restrict__ wcomb,
    const float* __restrict__ badj,
    const unsigned short* __restrict__ whhP,
    const float* __restrict__ bhhf,
    const float* __restrict__ bhhb,
    const int* __restrict__ flag,
    unsigned short* __restrict__ ycat) {
  const int dir = blockIdx.x & 1;
  const int b = blockIdx.x >> 1;
  const unsigned short* whh = whhP + (long)dir * (768 * 256);
  const float* bhh = dir ? bhhb : bhhf;
  const unsigned short* wcd = wcomb + (long)dir * (768 * 256);
  const float* bcd = badj + dir * 768;
  const int tid = threadIdx.x;
  const int wv = tid >> 6;        // 0..3
  const int lane = tid & 63;
  const int fr = lane & 15;
  const int fq = lane >> 4;
  const int fb = flag[b];

  // resident permuted recurrent weights: wave wv -> rows (wv*12+j)*16 + fr
  half8 wf[12][8];
#pragma unroll
  for (int j = 0; j < 12; ++j) {
    const unsigned short* wrow =
        whh + (long)((wv * 12 + j) * 16 + fr) * 256 + fq * 8;
#pragma unroll
    for (int s = 0; s < 8; ++s) wf[j][s] = *(const half8*)(wrow + s * 32);
  }
  // split pin across the unified file: tiles 0..7 -> AGPR (8*32=256 regs),
  // tiles 8..11 -> VGPR (128 regs). Opaque defs block remat-from-memory.
#pragma unroll
  for (int j = 0; j < 8; ++j)
#pragma unroll
    for (int s = 0; s < 8; ++s) asm volatile("" : "+a"(wf[j][s]));
#pragma unroll
  for (int j = 8; j < 12; ++j)
#pragma unroll
    for (int s = 0; s < 8; ++s) asm volatile("" : "+v"(wf[j][s]));

  __shared__ unsigned short xplds[CH][768];   // 48 KiB
  __shared__ unsigned short ylds[CH][256];    // 16 KiB
  __shared__ unsigned short hbuf[2][272];     // dbuf h + 16B zero pad @256

  float Bnh[4], h[4];
#pragma unroll
  for (int q = 0; q < 4; ++q) { Bnh[q] = 0.f; h[q] = 0.f; }
  if (lane < 16) {
#pragma unroll
    for (int q = 0; q < 4; ++q) Bnh[q] = bhh[512 + wv * 64 + q * 16 + fr];
  }
  hbuf[0][tid] = 0;
  if (tid < 16) {
    hbuf[0][256 + tid] = 0;
    hbuf[1][256 + tid] = 0;
  }
  __syncthreads();

  const long xnb = (long)b * 4096;
  unsigned short* yb = ycat + (long)b * (L_ * 512) + dir * 256;

  const f32x4 zero4 = {0.f, 0.f, 0.f, 0.f};
  int pb = 0;  // current h buffer

  for (int c = 0; c < NCH; ++c) {
    const int cc = dir ? (NCH - 1 - c) : c;
    const int t0 = cc * CH;

    // ---- flush previous chunk's y from LDS to global (skip first) ----
    if (c > 0) {
      const int pt0 = (dir ? (NCH - c) : (c - 1)) * CH;
#pragma unroll
      for (int k = 0; k < 4; ++k) {
        const int idx = tid + 256 * k;
        const int ts = idx >> 5;
        const int cl = (idx & 31) * 8;
        half8 v = *(const half8*)&ylds[ts][cl];
        *(half8*)(yb + (long)(pt0 + ts) * 512 + cl) = v;
      }
    }

    // ---- chunk GEMM: xplds = seq[t0..t0+31] @ wcd.T + bias ----
    const unsigned short* arow0;
    const unsigned short* arow1;
    {
      int t = t0 + fr;
      int p = fb ? (((t & 63) << 6) | (t >> 6)) : t;
      arow0 = xn + (xnb + p) * 256 + fq * 8;
      t = t0 + 16 + fr;
      p = fb ? (((t & 63) << 6) | (t >> 6)) : t;
      arow1 = xn + (xnb + p) * 256 + fq * 8;
    }
#pragma unroll
    for (int hf = 0; hf < 4; ++hf) {
      f32x4 acc0[3], acc1[3];
#pragma unroll
      for (int j = 0; j < 3; ++j) { acc0[j] = zero4; acc1[j] = zero4; }
#pragma unroll
      for (int s = 0; s < 8; ++s) {
        half8 a0 = *(const half8*)(arow0 + s * 32);
        half8 a1 = *(const half8*)(arow1 + s * 32);
#pragma unroll
        for (int j = 0; j < 3; ++j) {
          const int n = wv * 192 + hf * 48 + j * 16 + fr;
          half8 bfr = *(const half8*)(wcd + (long)n * 256 + s * 32 + fq * 8);
          acc0[j] = __builtin_amdgcn_mfma_f32_16x16x32_f16(a0, bfr, acc0[j], 0, 0, 0);
          acc1[j] = __builtin_amdgcn_mfma_f32_16x16x32_f16(a1, bfr, acc1[j], 0, 0, 0);
        }
      }
#pragma unroll
      for (int j = 0; j < 3; ++j) {
        const int n = wv * 192 + hf * 48 + j * 16 + fr;
        const float bv = bcd[n];
#pragma unroll
        for (int r = 0; r < 4; ++r) {
          xplds[fq * 4 + r][n] = f2h(acc0[j][r] + bv);
          xplds[16 + fq * 4 + r][n] = f2h(acc1[j][r] + bv);
        }
      }
    }
    __syncthreads();  // xplds ready; ylds free

    // ---- sequential GRU steps (ONE barrier each) ----
    for (int lt = 0; lt < CH; ++lt) {
      const int ts = dir ? (CH - 1 - lt) : lt;
      // prefetch gate inputs (independent of h)
      float xr[4], xz[4], xnv[4];
#pragma unroll
      for (int q = 0; q < 4; ++q) { xr[q] = 0.f; xz[q] = 0.f; xnv[q] = 0.f; }
      if (lane < 16) {
#pragma unroll
        for (int q = 0; q < 4; ++q) {
          const int u = wv * 64 + q * 16 + fr;
          xr[q] = h2f(xplds[ts][u]);
          xz[q] = h2f(xplds[ts][256 + u]);
          xnv[q] = h2f(xplds[ts][512 + u]);
        }
      }
      // gh = h @ whhP.T : M=16-padded MFMA, row 0 = h (lanes fr!=0 read the
      // 16B zero pad at offset 256 -> branchless zero rows).
      f32x4 acc[12];
#pragma unroll
      for (int j = 0; j < 12; ++j) acc[j] = zero4;
#pragma unroll
      for (int s = 0; s < 8; ++s) {
        const half8 a =
            *(const half8*)&hbuf[pb][(fr == 0) ? (s * 32 + fq * 8) : 256];
#pragma unroll
        for (int j = 0; j < 12; ++j)
          acc[j] = __builtin_amdgcn_mfma_f32_16x16x32_f16(a, wf[j][s], acc[j], 0, 0, 0);
      }
      // in-lane gate math: 4 units per lane (q=0..3)
      if (lane < 16) {
#pragma unroll
        for (int q = 0; q < 4; ++q) {
          const int u = wv * 64 + q * 16 + fr;
          float r = sigm(xr[q] + acc[q][0]);
          float z = sigm(xz[q] + acc[4 + q][0]);
          float n = tanhf_(xnv[q] + r * (acc[8 + q][0] + Bnh[q]));
          h[q] = n + z * (h[q] - n);
          unsigned short hb = f2h(h[q]);
          hbuf[pb ^ 1][u] = hb;
          ylds[ts][u] = hb;
        }
      }
      pb ^= 1;
      __syncthreads();
    }
  }
  // final chunk's y flush
  {
    const int pt0 = (dir ? 0 : (NCH - 1)) * CH;
#pragma unroll
    for (int k = 0; k < 4; ++k) {
      const int idx = tid + 256 * k;
      const int ts = idx >> 5;
      const int cl = (idx & 31) * 8;
      half8 v = *(const half8*)&ylds[ts][cl];
      *(half8*)(yb + (long)(pt0 + ts) * 512 + cl) = v;
    }
  }
}

// ------------------------------- launcher ----------------------------------
extern "C" void kernel_launch(void* const* d_in, const int* in_sizes, int n_in,
                              void* d_out, int out_size, void* d_ws, size_t ws_size,
                              hipStream_t stream) {
  (void)in_sizes; (void)n_in; (void)out_size; (void)ws_size;
  const float* x     = (const float*)d_in[0];
  const float* lng   = (const float*)d_in[1];
  const float* lnb   = (const float*)d_in[2];
  const float* w1    = (const float*)d_in[3];
  const float* b1    = (const float*)d_in[4];
  const float* w2    = (const float*)d_in[5];
  const float* b2    = (const float*)d_in[6];
  const float* in_w  = (const float*)d_in[7];
  const float* in_b  = (const float*)d_in[8];
  const float* wih_f = (const float*)d_in[9];
  const float* whh_f = (const float*)d_in[10];
  const float* bih_f = (const float*)d_in[11];
  const float* bhh_f = (const float*)d_in[12];
  const float* wih_b = (const float*)d_in[13];
  const float* whh_b = (const float*)d_in[14];
  const float* bih_b = (const float*)d_in[15];
  const float* bhh_b = (const float*)d_in[16];
  const float* out_w = (const float*)d_in[17];
  const float* out_b = (const float*)d_in[18];

  char* ws = (char*)d_ws;
  unsigned short* xn     = (unsigned short*)(ws + 0);
  float*          gray   = (float*)(ws + 33554432);
  int*            flag   = (int*)(ws + 33816576);
  unsigned short* whhP   = (unsigned short*)(ws + 33816832);
  unsigned short* outw16 = (unsigned short*)(ws + 34603264);
  unsigned short* wcomb  = (unsigned short*)(ws + 34865408);
  float*          badj   = (float*)(ws + 35651840);
  unsigned short* ycat   = (unsigned short*)(ws + 35658240);

  k_whhP<<<1536, 256, 0, stream>>>(whh_f, whh_b, whhP);
  k_f2h<<<512, 256, 0, stream>>>(out_w, outw16, 131072);
  k_wcomb<<<1536, 256, 0, stream>>>(wih_f, wih_b, in_w, wcomb);
  k_bcomb<<<6, 256, 0, stream>>>(wih_f, wih_b, in_b, bih_f, bih_b,
                                 bhh_f, bhh_b, badj);
  k_ln<<<16384, 256, 0, stream>>>(x, lng, lnb, xn, gray);
  k_sel<<<16, 256, 0, stream>>>(gray, w1, b1, w2, b2, flag);
  k_scan<<<32, 256, 0, stream>>>(xn, wcomb, badj, whhP,
                                 bhh_f, bhh_b, flag, ycat);
  dim3 gout(512, 2);
  k_gemm<<<gout, 256, 0, stream>>>(ycat, outw16, out_b, x, (float*)d_out, 512, 256);
}

// Round 7
// 6988.337 us; speedup vs baseline: 1.2964x; 1.1957x over previous
//
#include <hip/hip_runtime.h>

// ---------------------------------------------------------------------------
// FastCASSBlock: LN -> gradient-direction selector -> biGRU (input-proj fused
// into scan chunks) -> out_proj + residual.
// v7: v3's 8-wave geometry (32 WGs x 512 thr; 192 weight regs/wave) with a
// register diet (bias fold, plain addressing, tight transients) + opaque pin.
// Demand ~236/wave < 256 cap -> whh actually resident this time.
// Workspace layout (bytes), total ~98 MiB:
//   xn    f16 [65536,256]  @ 0           (33554432)
//   gray  f32 [65536]      @ 33554432    (262144)
//   flag  i32 [16]         @ 33816576    (256)
//   whh16 f16 [2][768,256] @ 33816832    (786432)   plain rows, dirs stacked
//   out_w f16 [256,512]    @ 34603264    (262144)
//   wcomb f16 [1536,256]   @ 34865408    (786432)
//   badj  f32 [1536]       @ 35651840    (6144)     bcomb + bhh folded (r,z)
//   ycat  f16 [65536,512]  @ 35658240    (67108864)
// ---------------------------------------------------------------------------

#define L_   4096
#define CH   32     // scan chunk length (steps)
#define NCH  128    // L_/CH

typedef __attribute__((ext_vector_type(8))) _Float16 half8;
typedef __attribute__((ext_vector_type(4))) float f32x4;

__device__ __forceinline__ unsigned short f2h(float f) {
  _Float16 h = (_Float16)f;
  return __builtin_bit_cast(unsigned short, h);
}
__device__ __forceinline__ float h2f(unsigned short u) {
  return (float)__builtin_bit_cast(_Float16, u);
}
__device__ __forceinline__ float sigm(float x) {
  return __builtin_amdgcn_rcpf(1.f + __expf(-x));
}
__device__ __forceinline__ float tanhf_(float x) {
  return 1.f - 2.f * __builtin_amdgcn_rcpf(1.f + __expf(2.f * x));
}

// --------------------------- f32 -> f16 convert ----------------------------
__global__ __launch_bounds__(256) void k_f2h(const float* __restrict__ in,
                                             unsigned short* __restrict__ out,
                                             int n) {
  int i = blockIdx.x * 256 + threadIdx.x;
  if (i < n) out[i] = f2h(in[i]);
}

// ------------------- wcomb[n,c] = sum_j wih[n,j]*in_w[j,c] -----------------
__global__ __launch_bounds__(256) void k_wcomb(const float* __restrict__ wih_f,
                                               const float* __restrict__ wih_b,
                                               const float* __restrict__ in_w,
                                               unsigned short* __restrict__ wcomb) {
  const int n = blockIdx.x;  // 0..1535
  const float* wrow = (n < 768) ? (wih_f + (long)n * 512)
                                : (wih_b + (long)(n - 768) * 512);
  const int k = threadIdx.x;  // 0..255
  float acc = 0.f;
  for (int j = 0; j < 512; ++j) acc += wrow[j] * in_w[j * 256 + k];
  wcomb[(long)n * 256 + k] = f2h(acc);
}

// -- badj[n] = bih[n] + sum_j wih[n,j]*in_b[j] (+ bhh[n] for r/z slots) ------
__global__ __launch_bounds__(256) void k_bcomb(const float* __restrict__ wih_f,
                                               const float* __restrict__ wih_b,
                                               const float* __restrict__ in_b,
                                               const float* __restrict__ bih_f,
                                               const float* __restrict__ bih_b,
                                               const float* __restrict__ bhh_f,
                                               const float* __restrict__ bhh_b,
                                               float* __restrict__ badj) {
  int n = blockIdx.x * 256 + threadIdx.x;
  if (n >= 1536) return;
  const int dir = n >= 768;
  const int g = dir ? (n - 768) : n;
  const float* wrow = (dir ? wih_b : wih_f) + (long)g * 512;
  float acc = (dir ? bih_b : bih_f)[g];
  for (int j = 0; j < 512; ++j) acc += wrow[j] * in_b[j];
  if (g < 512) acc += (dir ? bhh_b : bhh_f)[g];  // fold bhh for r,z gates
  badj[n] = acc;
}

// --------------------------- LayerNorm + gray ------------------------------
__global__ __launch_bounds__(256) void k_ln(const float* __restrict__ x,
                                            const float* __restrict__ gamma,
                                            const float* __restrict__ beta,
                                            unsigned short* __restrict__ xn,
                                            float* __restrict__ gray) {
  const int lane = threadIdx.x & 63;
  const long pix = (long)blockIdx.x * 4 + (threadIdx.x >> 6);
  const float4 v = *(const float4*)(x + pix * 256 + lane * 4);
  float s = v.x + v.y + v.z + v.w;
  float s2 = v.x * v.x + v.y * v.y + v.z * v.z + v.w * v.w;
#pragma unroll
  for (int off = 32; off > 0; off >>= 1) {
    s += __shfl_xor(s, off, 64);
    s2 += __shfl_xor(s2, off, 64);
  }
  const float mu = s * (1.f / 256.f);
  const float var = fmaxf(s2 * (1.f / 256.f) - mu * mu, 0.f);
  const float rstd = rsqrtf(var + 1e-5f);
  const float4 gm = *(const float4*)(gamma + lane * 4);
  const float4 bt = *(const float4*)(beta + lane * 4);
  float o0 = (v.x - mu) * rstd * gm.x + bt.x;
  float o1 = (v.y - mu) * rstd * gm.y + bt.y;
  float o2 = (v.z - mu) * rstd * gm.z + bt.z;
  float o3 = (v.w - mu) * rstd * gm.w + bt.w;
  ushort4 o;
  o.x = f2h(o0); o.y = f2h(o1); o.z = f2h(o2); o.w = f2h(o3);
  *(ushort4*)(xn + pix * 256 + lane * 4) = o;
  float gs = o0 + o1 + o2 + o3;
#pragma unroll
  for (int off = 32; off > 0; off >>= 1) gs += __shfl_xor(gs, off, 64);
  if (lane == 0) gray[pix] = gs * (1.f / 256.f);
}

// --------------------- gradient-direction selector -------------------------
__device__ __forceinline__ int refl64(int m) {
  return m < 0 ? -m : (m > 63 ? 126 - m : m);
}

__global__ __launch_bounds__(256) void k_sel(const float* __restrict__ gray,
                                             const float* __restrict__ w1,
                                             const float* __restrict__ b1,
                                             const float* __restrict__ w2,
                                             const float* __restrict__ b2,
                                             int* __restrict__ flag) {
  __shared__ float g[64][65];
  __shared__ float part[4][4];
  const int b = blockIdx.x;
  const int tid = threadIdx.x;
  for (int r = 0; r < 16; ++r) {
    int p = tid + 256 * r;
    g[p >> 6][p & 63] = gray[(long)b * 4096 + p];
  }
  __syncthreads();
  const float S = 66.f / 64.f;
  float sh = 0.f, sv = 0.f, sd = 0.f, sa = 0.f;
  for (int rr = 0; rr < 16; ++rr) {
    int p = tid + 256 * rr;
    int h = p >> 6, w = p & 63;
    float srci = (h + 0.5f) * S - 0.5f;
    int i0 = (int)srci;
    float ai = srci - (float)i0;
    int i1 = i0 + 1; if (i1 > 65) i1 = 65;
    int r0 = refl64(i0 - 1), r1 = refl64(i1 - 1);
    int wl = w ? (w - 1) : 1;
    int wr2 = (w == 63) ? 62 : (w + 1);
    float GH0 = fabsf(g[r0][wr2] - g[r0][wl]);
    float GH1 = fabsf(g[r1][wr2] - g[r1][wl]);
    float ghr = GH0 + ai * (GH1 - GH0);
    float srcj = (w + 0.5f) * S - 0.5f;
    int j0 = (int)srcj;
    float aj = srcj - (float)j0;
    int j1 = j0 + 1; if (j1 > 65) j1 = 65;
    int c0 = refl64(j0 - 1), c1 = refl64(j1 - 1);
    int hu = h ? (h - 1) : 1;
    int hd = (h == 63) ? 62 : (h + 1);
    float GV0 = fabsf(g[hd][c0] - g[hu][c0]);
    float GV1 = fabsf(g[hd][c1] - g[hu][c1]);
    float gvr = GV0 + aj * (GV1 - GV0);
    float wt = ((h == 0 || h == 63) ? 2.f : 3.f) *
               ((w == 0 || w == 63) ? 2.f : 3.f);
    sh += wt * ghr;
    sv += wt * gvr;
    sd += wt * 0.5f * (ghr + gvr);
    sa += wt * fabsf(ghr - gvr);
  }
#pragma unroll
  for (int off = 32; off > 0; off >>= 1) {
    sh += __shfl_xor(sh, off, 64);
    sv += __shfl_xor(sv, off, 64);
    sd += __shfl_xor(sd, off, 64);
    sa += __shfl_xor(sa, off, 64);
  }
  if ((tid & 63) == 0) {
    part[tid >> 6][0] = sh; part[tid >> 6][1] = sv;
    part[tid >> 6][2] = sd; part[tid >> 6][3] = sa;
  }
  __syncthreads();
  if (tid == 0) {
    float sc[4];
    for (int k = 0; k < 4; ++k)
      sc[k] = (part[0][k] + part[1][k] + part[2][k] + part[3][k]) * (1.f / 36864.f);
    float logits[4];
    for (int k = 0; k < 4; ++k) logits[k] = b2[k];
    for (int j = 0; j < 32; ++j) {
      float hj = b1[j];
      for (int i = 0; i < 4; ++i) hj += sc[i] * w1[j * 4 + i];
      hj = fmaxf(hj, 0.f);
      for (int k = 0; k < 4; ++k) logits[k] += hj * w2[k * 32 + j];
    }
    int idx = 0;
    float best = logits[0];
    for (int k = 1; k < 4; ++k)
      if (logits[k] > best) { best = logits[k]; idx = k; }
    flag[b] = (idx == 1) ? 1 : 0;
  }
}

// --------------------------- out-proj GEMM ---------------------------------
__global__ __launch_bounds__(256) void k_gemm(const unsigned short* __restrict__ A,
                                              const unsigned short* __restrict__ Bw,
                                              const float* __restrict__ bias,
                                              const float* __restrict__ resid,
                                              float* __restrict__ out,
                                              int K, int N) {
  __shared__ unsigned short Al[128][40];
  __shared__ unsigned short Bl[128][40];
  const int tid = threadIdx.x;
  const long m0 = (long)blockIdx.x * 128;
  const int n0 = blockIdx.y * 128;
  const int rA = tid >> 2;
  const int cp = (tid & 3) * 8;

  const unsigned short* a0p = A + (m0 + rA) * K + cp;
  const unsigned short* a1p = A + (m0 + rA + 64) * K + cp;
  const unsigned short* b0p = Bw + (long)(n0 + rA) * K + cp;
  const unsigned short* b1p = Bw + (long)(n0 + rA + 64) * K + cp;

  const int wv = tid >> 6, lane = tid & 63;
  const int wm = (wv >> 1) * 64, wn = (wv & 1) * 64;
  const int fr = lane & 15, fq = lane >> 4;

  const f32x4 zero4 = {0.f, 0.f, 0.f, 0.f};
  f32x4 acc[4][4];
#pragma unroll
  for (int i = 0; i < 4; ++i)
#pragma unroll
    for (int j = 0; j < 4; ++j) acc[i][j] = zero4;

  for (int k0 = 0; k0 < K; k0 += 32) {
    half8 va0 = *(const half8*)(a0p + k0);
    half8 va1 = *(const half8*)(a1p + k0);
    half8 vb0 = *(const half8*)(b0p + k0);
    half8 vb1 = *(const half8*)(b1p + k0);
    __syncthreads();
    *(half8*)&Al[rA][cp] = va0;
    *(half8*)&Al[rA + 64][cp] = va1;
    *(half8*)&Bl[rA][cp] = vb0;
    *(half8*)&Bl[rA + 64][cp] = vb1;
    __syncthreads();
    half8 af[4], bf[4];
#pragma unroll
    for (int i = 0; i < 4; ++i) af[i] = *(const half8*)&Al[wm + i * 16 + fr][fq * 8];
#pragma unroll
    for (int j = 0; j < 4; ++j) bf[j] = *(const half8*)&Bl[wn + j * 16 + fr][fq * 8];
#pragma unroll
    for (int i = 0; i < 4; ++i)
#pragma unroll
      for (int j = 0; j < 4; ++j)
        acc[i][j] = __builtin_amdgcn_mfma_f32_16x16x32_f16(af[i], bf[j], acc[i][j], 0, 0, 0);
  }

#pragma unroll
  for (int j = 0; j < 4; ++j) {
    const int col = n0 + wn + j * 16 + fr;
    const float bv = bias[col];
#pragma unroll
    for (int i = 0; i < 4; ++i) {
      const long mbase = m0 + wm + i * 16 + fq * 4;
#pragma unroll
      for (int r = 0; r < 4; ++r) {
        const long m = mbase + r;
        out[m * N + col] = acc[i][j][r] + bv + resid[m * N + col];
      }
    }
  }
}

// ------------------------------- GRU scan v7 --------------------------------
// One WG per (batch, direction): 32 WGs, 512 threads (8 waves).
// Wave wv owns units u in [wv*32, wv*32+32). wf[6][8] (192 regs/lane) holds
// whh rows n = gt*256 + wv*32 + q*16 + fr for j = gt*2+q (plain addressing --
// the permutation is the address computation). Opaque "+v" pin blocks remat.
// After the M=16-padded MFMA chain, lane l<16 holds gh[gt][wv*32+q*16+l] in
// acc[gt*2+q][0]; gate math in-lane; one barrier/step; biases pre-folded into
// xplds (badj) so the step loop carries only Bnh0/Bnh1 + h0/h1.
__global__ __launch_bounds__(512, 2) void k_scan(
    const unsigned short* __restrict__ xn,
    const unsigned short* __restrict__ wcomb,
    const float* __restrict__ badj,
    const unsigned short* __restrict__ whh16,
    const float* __restrict__ bhhf,
    const float* __restrict__ bhhb,
    const int* __restrict__ flag,
    unsigned short* __restrict__ ycat) {
  const int dir = blockIdx.x & 1;
  const int b = blockIdx.x >> 1;
  const unsigned short* whh = whh16 + (long)dir * (768 * 256);
  const float* bhh = dir ? bhhb : bhhf;
  const unsigned short* wcd = wcomb + (long)dir * (768 * 256);
  const float* bcd = badj + dir * 768;
  const int tid = threadIdx.x;
  const int wv = tid >> 6;        // 0..7
  const int lane = tid & 63;
  const int fr = lane & 15;
  const int fq = lane >> 4;
  const int fb = flag[b];

  // resident recurrent weights: j = gt*2+q -> whh row gt*256 + wv*32 + q*16 + fr
  half8 wf[6][8];
#pragma unroll
  for (int j = 0; j < 6; ++j) {
    const int n = (j >> 1) * 256 + wv * 32 + (j & 1) * 16 + fr;
    const unsigned short* wrow = whh + (long)n * 256 + fq * 8;
#pragma unroll
    for (int s = 0; s < 8; ++s) wf[j][s] = *(const half8*)(wrow + s * 32);
  }
  // opaque pin: forces register allocation, blocks remat-from-memory
#pragma unroll
  for (int j = 0; j < 6; ++j)
#pragma unroll
    for (int s = 0; s < 8; ++s) asm volatile("" : "+v"(wf[j][s]));

  __shared__ unsigned short xplds[CH][768];   // 48 KiB
  __shared__ unsigned short ylds[CH][256];    // 16 KiB
  __shared__ unsigned short hbuf[2][272];     // dbuf h + 16B zero pad @256

  const int u0 = wv * 32 + fr;
  float Bnh0 = 0.f, Bnh1 = 0.f, h0 = 0.f, h1 = 0.f;
  if (lane < 16) {
    Bnh0 = bhh[512 + u0];
    Bnh1 = bhh[512 + u0 + 16];
  }
  if (tid < 272) hbuf[0][tid] = 0;
  if (tid < 16) hbuf[1][256 + tid] = 0;
  __syncthreads();

  const long xnb = (long)b * 4096;
  unsigned short* yb = ycat + (long)b * (L_ * 512) + dir * 256;

  const f32x4 zero4 = {0.f, 0.f, 0.f, 0.f};
  int pb = 0;  // current h buffer

  for (int c = 0; c < NCH; ++c) {
    const int cc = dir ? (NCH - 1 - c) : c;
    const int t0 = cc * CH;

    // ---- flush previous chunk's y from LDS to global (skip first) ----
    if (c > 0) {
      const int pt0 = (dir ? (NCH - c) : (c - 1)) * CH;
#pragma unroll
      for (int k = 0; k < 2; ++k) {
        const int idx = tid * 2 + k;
        const int ts = idx >> 5;
        const int cl = (idx & 31) * 8;
        half8 v = *(const half8*)&ylds[ts][cl];
        *(half8*)(yb + (long)(pt0 + ts) * 512 + cl) = v;
      }
    }

    // ---- chunk GEMM: xplds = seq[t0..t0+31] @ wcd.T + badj ----
    const unsigned short* arow0;
    const unsigned short* arow1;
    {
      int t = t0 + fr;
      int p = fb ? (((t & 63) << 6) | (t >> 6)) : t;
      arow0 = xn + (xnb + p) * 256 + fq * 8;
      t = t0 + 16 + fr;
      p = fb ? (((t & 63) << 6) | (t >> 6)) : t;
      arow1 = xn + (xnb + p) * 256 + fq * 8;
    }
#pragma unroll
    for (int hf = 0; hf < 2; ++hf) {
      f32x4 acc0[3], acc1[3];
#pragma unroll
      for (int i = 0; i < 3; ++i) { acc0[i] = zero4; acc1[i] = zero4; }
#pragma unroll
      for (int s = 0; s < 8; ++s) {
        half8 a0 = *(const half8*)(arow0 + s * 32);
        half8 a1 = *(const half8*)(arow1 + s * 32);
#pragma unroll
        for (int i = 0; i < 3; ++i) {
          const int jj = hf * 3 + i;
          const int n = (jj >> 1) * 256 + wv * 32 + (jj & 1) * 16 + fr;
          half8 bfr = *(const half8*)(wcd + (long)n * 256 + s * 32 + fq * 8);
          acc0[i] = __builtin_amdgcn_mfma_f32_16x16x32_f16(a0, bfr, acc0[i], 0, 0, 0);
          acc1[i] = __builtin_amdgcn_mfma_f32_16x16x32_f16(a1, bfr, acc1[i], 0, 0, 0);
        }
      }
#pragma unroll
      for (int i = 0; i < 3; ++i) {
        const int jj = hf * 3 + i;
        const int n = (jj >> 1) * 256 + wv * 32 + (jj & 1) * 16 + fr;
        const float bv = bcd[n];
#pragma unroll
        for (int r = 0; r < 4; ++r) {
          xplds[fq * 4 + r][n] = f2h(acc0[i][r] + bv);
          xplds[16 + fq * 4 + r][n] = f2h(acc1[i][r] + bv);
        }
      }
    }
    __syncthreads();  // xplds ready; ylds free

    // ---- sequential GRU steps (ONE barrier each) ----
    for (int lt = 0; lt < CH; ++lt) {
      const int ts = dir ? (CH - 1 - lt) : lt;
      // prefetch gate inputs (independent of h; biases pre-folded)
      float xr0 = 0.f, xr1 = 0.f, xz0 = 0.f, xz1 = 0.f, xn0 = 0.f, xn1 = 0.f;
      if (lane < 16) {
        xr0 = h2f(xplds[ts][u0]);
        xr1 = h2f(xplds[ts][u0 + 16]);
        xz0 = h2f(xplds[ts][256 + u0]);
        xz1 = h2f(xplds[ts][256 + u0 + 16]);
        xn0 = h2f(xplds[ts][512 + u0]);
        xn1 = h2f(xplds[ts][512 + u0 + 16]);
      }
      // gh = h @ whh.T : M=16-padded MFMA, row 0 = h (lanes fr!=0 read the
      // 16B zero pad at offset 256 -> branchless zero rows).
      f32x4 acc[6];
#pragma unroll
      for (int j = 0; j < 6; ++j) acc[j] = zero4;
#pragma unroll
      for (int s = 0; s < 8; ++s) {
        const half8 a =
            *(const half8*)&hbuf[pb][(fr == 0) ? (s * 32 + fq * 8) : 256];
#pragma unroll
        for (int j = 0; j < 6; ++j)
          acc[j] = __builtin_amdgcn_mfma_f32_16x16x32_f16(a, wf[j][s], acc[j], 0, 0, 0);
      }
      // in-lane gate math for units u0, u0+16
      if (lane < 16) {
        float r0 = sigm(xr0 + acc[0][0]);
        float r1 = sigm(xr1 + acc[1][0]);
        float z0 = sigm(xz0 + acc[2][0]);
        float z1 = sigm(xz1 + acc[3][0]);
        float n0 = tanhf_(xn0 + r0 * (acc[4][0] + Bnh0));
        float n1 = tanhf_(xn1 + r1 * (acc[5][0] + Bnh1));
        h0 = n0 + z0 * (h0 - n0);
        h1 = n1 + z1 * (h1 - n1);
        unsigned short hb0 = f2h(h0);
        unsigned short hb1 = f2h(h1);
        hbuf[pb ^ 1][u0] = hb0;
        hbuf[pb ^ 1][u0 + 16] = hb1;
        ylds[ts][u0] = hb0;
        ylds[ts][u0 + 16] = hb1;
      }
      pb ^= 1;
      __syncthreads();
    }
  }
  // final chunk's y flush
  {
    const int pt0 = (dir ? 0 : (NCH - 1)) * CH;
#pragma unroll
    for (int k = 0; k < 2; ++k) {
      const int idx = tid * 2 + k;
      const int ts = idx >> 5;
      const int cl = (idx & 31) * 8;
      half8 v = *(const half8*)&ylds[ts][cl];
      *(half8*)(yb + (long)(pt0 + ts) * 512 + cl) = v;
    }
  }
}

// ------------------------------- launcher ----------------------------------
extern "C" void kernel_launch(void* const* d_in, const int* in_sizes, int n_in,
                              void* d_out, int out_size, void* d_ws, size_t ws_size,
                              hipStream_t stream) {
  (void)in_sizes; (void)n_in; (void)out_size; (void)ws_size;
  const float* x     = (const float*)d_in[0];
  const float* lng   = (const float*)d_in[1];
  const float* lnb   = (const float*)d_in[2];
  const float* w1    = (const float*)d_in[3];
  const float* b1    = (const float*)d_in[4];
  const float* w2    = (const float*)d_in[5];
  const float* b2    = (const float*)d_in[6];
  const float* in_w  = (const float*)d_in[7];
  const float* in_b  = (const float*)d_in[8];
  const float* wih_f = (const float*)d_in[9];
  const float* whh_f = (const float*)d_in[10];
  const float* bih_f = (const float*)d_in[11];
  const float* bhh_f = (const float*)d_in[12];
  const float* wih_b = (const float*)d_in[13];
  const float* whh_b = (const float*)d_in[14];
  const float* bih_b = (const float*)d_in[15];
  const float* bhh_b = (const float*)d_in[16];
  const float* out_w = (const float*)d_in[17];
  const float* out_b = (const float*)d_in[18];

  char* ws = (char*)d_ws;
  unsigned short* xn     = (unsigned short*)(ws + 0);
  float*          gray   = (float*)(ws + 33554432);
  int*            flag   = (int*)(ws + 33816576);
  unsigned short* whh16  = (unsigned short*)(ws + 33816832);
  unsigned short* outw16 = (unsigned short*)(ws + 34603264);
  unsigned short* wcomb  = (unsigned short*)(ws + 34865408);
  float*          badj   = (float*)(ws + 35651840);
  unsigned short* ycat   = (unsigned short*)(ws + 35658240);

  k_f2h<<<768, 256, 0, stream>>>(whh_f, whh16, 196608);
  k_f2h<<<768, 256, 0, stream>>>(whh_b, whh16 + 196608, 196608);
  k_f2h<<<512, 256, 0, stream>>>(out_w, outw16, 131072);
  k_wcomb<<<1536, 256, 0, stream>>>(wih_f, wih_b, in_w, wcomb);
  k_bcomb<<<6, 256, 0, stream>>>(wih_f, wih_b, in_b, bih_f, bih_b,
                                 bhh_f, bhh_b, badj);
  k_ln<<<16384, 256, 0, stream>>>(x, lng, lnb, xn, gray);
  k_sel<<<16, 256, 0, stream>>>(gray, w1, b1, w2, b2, flag);
  k_scan<<<32, 512, 0, stream>>>(xn, wcomb, badj, whh16,
                                 bhh_f, bhh_b, flag, ycat);
  dim3 gout(512, 2);
  k_gemm<<<gout, 256, 0, stream>>>(ycat, outw16, out_b, x, (float*)d_out, 512, 256);
}